// Round 1
// baseline (187.844 us; speedup 1.0000x reference)
//
#include <hip/hip_runtime.h>
#include <cstdint>
#include <cstddef>

// Problem constants (fixed by the reference)
#define B_DIM 8192
#define C_DIM 4096
#define F_DIM 1024
#define O_DIM 10
#define NSLICE 16  // C_DIM / 256 partial slices

typedef __attribute__((ext_vector_type(8))) __bf16 bf16x8;
typedef __attribute__((ext_vector_type(8))) unsigned short ushort8;
typedef __attribute__((ext_vector_type(4))) float f32x4;

// ---------------------------------------------------------------------------
// fp32 -> bf16 round-to-nearest-even
__device__ __forceinline__ unsigned short f2bf(float f) {
  unsigned int u = __builtin_bit_cast(unsigned int, f);
  u += 0x7fffu + ((u >> 16) & 1u);
  return (unsigned short)(u >> 16);
}

// ---------------------------------------------------------------------------
// Wave-per-row prep: rows [0,B_DIM) = x, rows [B_DIM, B_DIM+C_DIM) = loc.
// Converts fp32 row -> bf16 and computes fp32 ||row||^2. No LDS, no barrier.
__global__ __launch_bounds__(512) void prep_merged(
    const float* __restrict__ x, const float* __restrict__ loc,
    unsigned short* __restrict__ xb, unsigned short* __restrict__ locb,
    float* __restrict__ x2, float* __restrict__ c2) {
  const int wave = threadIdx.x >> 6;
  const int lane = threadIdx.x & 63;
  const int row = blockIdx.x * 8 + wave;
  const float* src;
  unsigned short* dst;
  float* nrm;
  if (row < B_DIM) {
    src = x + (size_t)row * F_DIM;
    dst = xb + (size_t)row * F_DIM;
    nrm = x2 + row;
  } else {
    const int r = row - B_DIM;
    src = loc + (size_t)r * F_DIM;
    dst = locb + (size_t)r * F_DIM;
    nrm = c2 + r;
  }
  float ss = 0.f;
#pragma unroll
  for (int i = 0; i < 4; ++i) {
    const float4 v = reinterpret_cast<const float4*>(src)[lane + 64 * i];
    ss += v.x * v.x + v.y * v.y + v.z * v.z + v.w * v.w;
    ushort4 o;
    o.x = f2bf(v.x); o.y = f2bf(v.y); o.z = f2bf(v.z); o.w = f2bf(v.w);
    reinterpret_cast<ushort4*>(dst)[lane + 64 * i] = o;
  }
#pragma unroll
  for (int m = 1; m <= 32; m <<= 1) ss += __shfl_xor(ss, m, 64);
  if (lane == 0) *nrm = ss;
}

// ---------------------------------------------------------------------------
// Fused: S = loc_bf16 @ x_bf16^T (MFMA), phi = exp(-sqrt(max(c2+x2-2S,0))/scale),
// P[slice][b][o] = sum_{c in 256-slice} phi[c][b] * w[o][c]   (no atomics).
//
// Tile: 256 c (M) x 256 b (N), BK=64; 512 threads = 8 waves in (c-half 2) x
// (b-quarter 4); each wave 128x64 via 8x4 grid of 16x16x32 MFMAs x 2 k-substeps.
//
// K-loop: 8-PHASE schedule (learn_hip m201/T3+T4+T5). One iteration covers
// TWO K-tiles (buf0 = tile 2i, buf1 = tile 2i+1; buffers fixed, no pingpong
// variable). Each K-tile is 4 quadrant phases in order (qi,qj) =
// (0,0),(0,1),(1,1),(1,0) with A/B fragments REUSED in registers across
// phases (24 ds_read_b128 per K-tile total). Each phase:
//   { ds_read quadrant frags | stage ONE 16KB half-tile (2 glds/thread) }
//   s_barrier; lgkmcnt(0); sched_barrier; setprio(1); 16 MFMA; setprio(0);
//   s_barrier
// vmcnt is COUNTED, never drained in the loop: vmcnt(6) at phases 3 and 7
// (3 half-tiles = 6 loads stay in flight), vmcnt(0) only in the peeled last
// iteration. Stage targets are regions whose last LDS read retired before
// the previous phase's end barrier:
//   ph0: A1(t1->buf1)  ph1: B0(t2->buf0)  ph2: A0(t2->buf0)
//   ph3: B1(t2->buf0)+vmcnt(6)            ph4: A1(t2->buf0)
//   ph5: B0(t3->buf1)  ph6: A0(t3->buf1)  ph7: B1(t3->buf1)+vmcnt(6)
// where region An = A-rows of quadrant qi=n ({0-63,128-191} / {64-127,
// 192-255}), Bn = B-rows of quadrant qj=n ({q*64+0..31} / {q*64+32..63}).
//
// XCD swizzle: blockIdx&7 = XCD; c-neighbors (2g,2g+1) sharing a b-tile are
// adjacent ids -> co-resident on one XCD -> L2 captures the pair.
__global__ __launch_bounds__(512, 2) void rbf_fused(
    const unsigned short* __restrict__ locb,  // [C_DIM][F_DIM] bf16 bits
    const unsigned short* __restrict__ xb,    // [B_DIM][F_DIM] bf16 bits
    const float* __restrict__ c2,             // [C_DIM]
    const float* __restrict__ x2,             // [B_DIM]
    const float* __restrict__ scale,          // [C_DIM]
    const float* __restrict__ w,              // [O_DIM][C_DIM]
    float* __restrict__ P) {                  // [NSLICE][B_DIM][O_DIM]
  extern __shared__ unsigned short smem[];
  unsigned short* As = smem;              // 2 x 256x64 = 64 KB
  unsigned short* Bs = smem + 2 * 16384;  // 2 x 256x64 = 64 KB

  const int tid = threadIdx.x;
  const int wave = tid >> 6;
  const int lane = tid & 63;
  const int quad = lane >> 4;
  const int n15 = lane & 15;
  const int n7 = n15 & 7;

  // XCD-aware mapping: g = XCD, cIdx in {2g, 2g+1} fastest, then bIdx.
  const int id = blockIdx.x;
  const int g = id & 7;
  const int j = id >> 3;
  const int cIdx = (g << 1) + (j & 1);  // 0..15
  const int bIdx = j >> 1;              // 0..31
  const int cBase = cIdx << 8;
  const int bBase = bIdx << 8;

  const int wch = wave >> 2;  // c-half 0/1
  const int bq = wave & 3;    // b-quarter 0..3
  const int wcc = wch * 128;  // wave centroid offset in tile
  const int wbb = bq * 64;    // wave batch offset in tile

  float x2v[4];
#pragma unroll
  for (int tj = 0; tj < 4; ++tj) x2v[tj] = x2[bBase + wbb + tj * 16 + n15];

  // Staging: each half-tile is 128 rows x 64 k (16 KB) = 16 chunks of 1 KB
  // (8 rows x 128 B); each wave stages 2 chunks = 2 global_load_lds/thread.
  // Within a chunk: lane l -> row l>>3, physical 16-B slot l&7; global
  // k-chunk q = (l&7)^((l>>3)&7)  (XOR swizzle over 8 slots; reader matches,
  // giving full 32-bank spread for ds_read_b128). LDS dest is linear
  // (chunk base = row*64 elems + lane*16B) as global_load_lds requires.
  const int rowIn = lane >> 3;                              // 0..7
  const int colOff = ((lane & 7) ^ ((lane >> 3) & 7)) * 8;  // bf16 elems

  // Chunk descriptors: [half h][chunk c] per matrix. Consumed-set layout:
  //   A half h rows: (idx>>3)*128 + h*64 + (idx&7)*8,  idx = wave*2+c
  //   B half h rows: (idx>>2)*64  + h*32 + (idx&3)*8
  const unsigned short* aPtr[2][2];
  const unsigned short* bPtr[2][2];
  int aLds[2][2], bLds[2][2];
#pragma unroll
  for (int c = 0; c < 2; ++c) {
    const int idx = (wave << 1) + c;
    const int rA = ((idx >> 3) << 7) + ((idx & 7) << 3);
    const int rB = ((idx >> 2) << 6) + ((idx & 3) << 3);
#pragma unroll
    for (int h = 0; h < 2; ++h) {
      const int ra = rA + (h << 6);
      const int rb = rB + (h << 5);
      aPtr[h][c] = locb + (size_t)(cBase + ra + rowIn) * F_DIM + colOff;
      aLds[h][c] = ra * 64 + lane * 8;
      bPtr[h][c] = xb + (size_t)(bBase + rb + rowIn) * F_DIM + colOff;
      bLds[h][c] = rb * 64 + lane * 8;
    }
  }

#define STAGE_A(p, h, t)                                                       \
  do {                                                                         \
    _Pragma("unroll") for (int cc_ = 0; cc_ < 2; ++cc_)                        \
        __builtin_amdgcn_global_load_lds(                                      \
            (const __attribute__((address_space(1))) void*)(aPtr[h][cc_] +     \
                                                            ((t) << 6)),       \
            (__attribute__((address_space(3))) void*)&As[(p)*16384 +           \
                                                         aLds[h][cc_]],        \
            16, 0, 0);                                                         \
  } while (0)

#define STAGE_B(p, h, t)                                                       \
  do {                                                                         \
    _Pragma("unroll") for (int cc_ = 0; cc_ < 2; ++cc_)                        \
        __builtin_amdgcn_global_load_lds(                                      \
            (const __attribute__((address_space(1))) void*)(bPtr[h][cc_] +     \
                                                            ((t) << 6)),       \
            (__attribute__((address_space(3))) void*)&Bs[(p)*16384 +           \
                                                         bLds[h][cc_]],        \
            16, 0, 0);                                                         \
  } while (0)

  // Fragment loads (quadrant granularity, persist across phases in regs).
#define LOAD_A(p, qi)                                                          \
  {                                                                            \
    _Pragma("unroll") for (int s_ = 0; s_ < 2; ++s_) {                         \
      const int slot_ = ((s_ * 4 + quad) ^ n7) * 8;                            \
      _Pragma("unroll") for (int ti_ = 0; ti_ < 4; ++ti_)                      \
          af[s_][ti_] = __builtin_bit_cast(                                    \
              bf16x8, *(const ushort8*)&As[(p)*16384 +                         \
                  (wcc + (qi)*64 + ti_ * 16 + n15) * 64 + slot_]);             \
    }                                                                          \
  }

#define LOAD_B(p, qj)                                                          \
  {                                                                            \
    _Pragma("unroll") for (int s_ = 0; s_ < 2; ++s_) {                         \
      const int slot_ = ((s_ * 4 + quad) ^ n7) * 8;                            \
      _Pragma("unroll") for (int tj_ = 0; tj_ < 2; ++tj_)                      \
          bfr[qj][s_][tj_] = __builtin_bit_cast(                               \
              bf16x8, *(const ushort8*)&Bs[(p)*16384 +                         \
                  (wbb + (qj)*32 + tj_ * 16 + n15) * 64 + slot_]);             \
    }                                                                          \
  }

  // Pre-MFMA barrier; lgkmcnt(0)+sched_barrier (rule #18); setprio cluster.
#define MMA(qi, qj)                                                            \
  __builtin_amdgcn_s_barrier();                                                \
  asm volatile("s_waitcnt lgkmcnt(0)" ::: "memory");                           \
  __builtin_amdgcn_sched_barrier(0);                                           \
  __builtin_amdgcn_s_setprio(1);                                               \
  _Pragma("unroll") for (int s_ = 0; s_ < 2; ++s_)                             \
      _Pragma("unroll") for (int ti_ = 0; ti_ < 4; ++ti_)                      \
          _Pragma("unroll") for (int tj_ = 0; tj_ < 2; ++tj_)                  \
              acc[(qi)*4 + ti_][(qj)*2 + tj_] =                                \
                  __builtin_amdgcn_mfma_f32_16x16x32_bf16(                     \
                      af[s_][ti_], bfr[qj][s_][tj_],                           \
                      acc[(qi)*4 + ti_][(qj)*2 + tj_], 0, 0, 0);               \
  __builtin_amdgcn_s_setprio(0);

  f32x4 acc[8][4];
  const f32x4 zero = {0.f, 0.f, 0.f, 0.f};
#pragma unroll
  for (int i = 0; i < 8; ++i)
#pragma unroll
    for (int jj = 0; jj < 4; ++jj) acc[i][jj] = zero;

  bf16x8 af[2][4];      // [sig][ti']  current qi's A fragments
  bf16x8 bfr[2][2][2];  // [qj][sig][tj']  both qj's B fragments

  // Prologue: tile0 fully into buf0; tile1's B0,A0,B1 into buf1 (A1 comes at
  // ph0 of iter 0, matching the steady-state schedule). Counted wait: the 6
  // newest (tile1) loads may stay in flight; tile0's 8 are guaranteed landed.
  STAGE_A(0, 0, 0);
  STAGE_A(0, 1, 0);
  STAGE_B(0, 0, 0);
  STAGE_B(0, 1, 0);
  STAGE_B(1, 0, 1);
  STAGE_A(1, 0, 1);
  STAGE_B(1, 1, 1);
  asm volatile("s_waitcnt vmcnt(6)" ::: "memory");
  __builtin_amdgcn_s_barrier();

  for (int it = 0; it < 7; ++it) {
    const int t1 = 2 * it + 1;
    const int t2 = t1 + 1;
    const int t3 = t1 + 2;
    // ---- K-tile 2it in buf0 ----
    // ph0: quad (0,0) — 12 ds_reads; stage A1(t1)->buf1 (free since prev ph6)
    LOAD_A(0, 0)
    LOAD_B(0, 0)
    STAGE_A(1, 1, t1);
    MMA(0, 0)
    __builtin_amdgcn_s_barrier();
    // ph1: quad (0,1) — 4 ds_reads; stage B0(t2)->buf0 (read only at ph0)
    LOAD_B(0, 1)
    STAGE_B(0, 0, t2);
    MMA(0, 1)
    __builtin_amdgcn_s_barrier();
    // ph2: quad (1,1) — 8 ds_reads; stage A0(t2)->buf0 (read only at ph0)
    LOAD_A(0, 1)
    STAGE_A(0, 0, t2);
    MMA(1, 1)
    __builtin_amdgcn_s_barrier();
    // ph3: quad (1,0) — 0 ds_reads (af qi=1 + bfr[0] reused from regs);
    // stage B1(t2)->buf0 (read at ph1). vmcnt(6): tile t1 (buf1) complete —
    // only the 6 t2-loads (ph1..ph3) may remain in flight.
    STAGE_B(0, 1, t2);
    MMA(1, 0)
    asm volatile("s_waitcnt vmcnt(6)" ::: "memory");
    __builtin_amdgcn_s_barrier();
    // ---- K-tile 2it+1 in buf1 ----
    // ph4: quad (0,0); stage A1(t2)->buf0 (read at ph2)
    LOAD_A(1, 0)
    LOAD_B(1, 0)
    STAGE_A(0, 1, t2);
    MMA(0, 0)
    __builtin_amdgcn_s_barrier();
    // ph5: quad (0,1); stage B0(t3)->buf1 (read at ph4)
    LOAD_B(1, 1)
    STAGE_B(1, 0, t3);
    MMA(0, 1)
    __builtin_amdgcn_s_barrier();
    // ph6: quad (1,1); stage A0(t3)->buf1 (read at ph4)
    LOAD_A(1, 1)
    STAGE_A(1, 0, t3);
    MMA(1, 1)
    __builtin_amdgcn_s_barrier();
    // ph7: quad (1,0); stage B1(t3)->buf1 (read at ph5). vmcnt(6): tile t2
    // (buf0) complete — only the 6 t3-loads (ph5..ph7) may remain.
    STAGE_B(1, 1, t3);
    MMA(1, 0)
    asm volatile("s_waitcnt vmcnt(6)" ::: "memory");
    __builtin_amdgcn_s_barrier();
  }
  // Peeled last iteration: tiles 14 (buf0) / 15 (buf1); only A1(15) left to
  // stage; single vmcnt(0) drain before reading tile 15.
  LOAD_A(0, 0)
  LOAD_B(0, 0)
  STAGE_A(1, 1, 15);
  MMA(0, 0)
  __builtin_amdgcn_s_barrier();
  LOAD_B(0, 1)
  MMA(0, 1)
  __builtin_amdgcn_s_barrier();
  LOAD_A(0, 1)
  MMA(1, 1)
  __builtin_amdgcn_s_barrier();
  MMA(1, 0)
  asm volatile("s_waitcnt vmcnt(0)" ::: "memory");
  __builtin_amdgcn_s_barrier();
  LOAD_A(1, 0)
  LOAD_B(1, 0)
  MMA(0, 0)
  __builtin_amdgcn_s_barrier();
  LOAD_B(1, 1)
  MMA(0, 1)
  __builtin_amdgcn_s_barrier();
  LOAD_A(1, 1)
  MMA(1, 1)
  __builtin_amdgcn_s_barrier();
  MMA(1, 0)
  __syncthreads();  // all waves done reading LDS before epilogue reuse

  // ---- epilogue ----
  // acc[ti][tj][r]: c_local = wcc+ti*16+quad*4+r, b_local = wbb+tj*16+n15.
  // Stage w / c2 / (-1/scale) into the dead As region (64 KB avail).
  float* wlds = reinterpret_cast<float*>(As);  // [O_DIM*256] = 10 KB
  float* c2l = wlds + O_DIM * 256;             // [256]
  float* nisl = c2l + 256;                     // [256]
  for (int i = tid; i < O_DIM * 256; i += 512)
    wlds[i] = w[(i >> 8) * C_DIM + cBase + (i & 255)];
  if (tid < 256) {
    c2l[tid] = c2[cBase + tid];
    nisl[tid] = -1.0f / scale[cBase + tid];
  }
  __syncthreads();

  float partial[4][O_DIM];
#pragma unroll
  for (int tj = 0; tj < 4; ++tj)
#pragma unroll
    for (int o = 0; o < O_DIM; ++o) partial[tj][o] = 0.f;

#pragma unroll
  for (int ti = 0; ti < 8; ++ti) {
    const int clq = wcc + ti * 16 + quad * 4;
    const f32x4 c24 = *(const f32x4*)&c2l[clq];
    const f32x4 ns4 = *(const f32x4*)&nisl[clq];
    float phi[4][4];  // [tj][r]
#pragma unroll
    for (int tj = 0; tj < 4; ++tj)
#pragma unroll
      for (int r = 0; r < 4; ++r) {
        const float s = acc[ti][tj][r];
        const float sq = fmaxf(x2v[tj] + c24[r] - 2.0f * s, 0.0f);
        phi[tj][r] = __expf(sqrtf(sq) * ns4[r]);
      }
#pragma unroll
    for (int o = 0; o < O_DIM; ++o) {
      const f32x4 w4 = *(const f32x4*)&wlds[o * 256 + clq];
#pragma unroll
      for (int tj = 0; tj < 4; ++tj)
#pragma unroll
        for (int r = 0; r < 4; ++r)
          partial[tj][o] = fmaf(phi[tj][r], w4[r], partial[tj][o]);
    }
  }

  // reduce over the 4 quads (lanes ^16, ^32 share the same batch index)
#pragma unroll
  for (int tj = 0; tj < 4; ++tj)
#pragma unroll
    for (int o = 0; o < O_DIM; ++o) {
      float v = partial[tj][o];
      v += __shfl_xor(v, 16, 64);
      v += __shfl_xor(v, 32, 64);
      partial[tj][o] = v;
    }

  // Cross-wave (c-halves) reduce via LDS (alias dead Bs), then store.
  float* red = reinterpret_cast<float*>(Bs);  // 2560 floats, region is dead
  if (wch == 0 && quad == 0) {
#pragma unroll
    for (int tj = 0; tj < 4; ++tj)
#pragma unroll
      for (int o = 0; o < O_DIM; ++o)
        red[(wbb + tj * 16 + n15) * O_DIM + o] = partial[tj][o];
  }
  __syncthreads();
  if (wch == 1 && quad == 0) {
#pragma unroll
    for (int tj = 0; tj < 4; ++tj)
#pragma unroll
      for (int o = 0; o < O_DIM; ++o)
        red[(wbb + tj * 16 + n15) * O_DIM + o] += partial[tj][o];
  }
  __syncthreads();
  float* Pdst = P + (size_t)cIdx * (B_DIM * O_DIM) + (size_t)bBase * O_DIM;
  for (int i = tid; i < 256 * O_DIM; i += 512) Pdst[i] = red[i];
}

// ---------------------------------------------------------------------------
// out[b][o] = sum_k P[k][b][o]
__global__ __launch_bounds__(256) void reduce_partials(const float* __restrict__ P,
                                                       float* __restrict__ out) {
  const int i = blockIdx.x * 256 + threadIdx.x;  // 0 .. B_DIM*O_DIM-1
  float s = 0.f;
#pragma unroll
  for (int k = 0; k < NSLICE; ++k) s += P[(size_t)k * (B_DIM * O_DIM) + i];
  out[i] = s;
}

// ---------------------------------------------------------------------------
extern "C" void kernel_launch(void* const* d_in, const int* in_sizes, int n_in,
                              void* d_out, int out_size, void* d_ws, size_t ws_size,
                              hipStream_t stream) {
  const float* x = (const float*)d_in[0];      // [8192,1024]
  const float* loc = (const float*)d_in[1];    // [4096,1024]
  const float* scale = (const float*)d_in[2];  // [4096]
  const float* w = (const float*)d_in[3];      // [10,4096]
  float* out = (float*)d_out;                  // [8192,10]

  // workspace layout (~30.3 MB)
  char* ws = (char*)d_ws;
  unsigned short* xb = (unsigned short*)(ws);                              // 16 MB
  unsigned short* locb = (unsigned short*)(ws + (size_t)16 * 1024 * 1024); // 8 MB
  float* x2 = (float*)(ws + (size_t)24 * 1024 * 1024);                    // 32 KB
  float* c2 = (float*)(ws + (size_t)24 * 1024 * 1024 + 64 * 1024);        // 16 KB
  float* P = (float*)(ws + (size_t)25 * 1024 * 1024);                     // 5.24 MB

  // 128 KB dynamic LDS (static cap is 64 KB). Host-side attribute set;
  // idempotent, not a stream op — safe under graph capture.
  hipFuncSetAttribute((const void*)rbf_fused,
                      hipFuncAttributeMaxDynamicSharedMemorySize, 131072);

  prep_merged<<<(B_DIM + C_DIM) / 8, 512, 0, stream>>>(x, loc, xb, locb, x2, c2);

  rbf_fused<<<NSLICE * 32, 512, 131072, stream>>>(locb, xb, c2, x2, scale, w, P);

  reduce_partials<<<(B_DIM * O_DIM) / 256, 256, 0, stream>>>(P, out);
}